// Round 7
// baseline (83.177 us; speedup 1.0000x reference)
//
#include <hip/hip_runtime.h>
#include <hip/hip_bf16.h>

// NT-Xent loss, MI355X. B=4096, D=256, N=8192, temp=0.5.
// normalize(+exp2 prescale) -> bf16 zn -> MFMA Gram with fused exp/LSE
// partials -> finalize.
// R7: NO LDS, NO barriers. R4-R6 counters showed serial-sum pipe behavior
// (MfmaUtil 30 + VALUBusy 22, dur ~= MFMA+LDS+VALU) caused by barrier
// lockstep at 2 waves/SIMD. B fragments now load straight from global
// (zn = 4MB = one XCD L2; per-jt working set 8KB -> L1/L2-hit), double-
// buffered one 16-col tile ahead in registers (b0/b1). Waves are fully
// independent -> natural anti-phase overlap of MFMA vs exp/loads.
// Block = 256 i-rows x 512 j-cols, 4 waves x 64 i-rows, A in regs
// (a[4][8]=128). ~240 VGPR -> 2 waves/SIMD, no spill (watch WRITE_SIZE).

typedef __attribute__((ext_vector_type(4))) float f32x4;
typedef __attribute__((ext_vector_type(8))) short s16x8;

#define N_TOT 8192
#define B_HALF 4096
#define D_DIM 256
#define JSPLIT 16
#define JCOLS 512
#define SCL_PRE 1.6986436f             // sqrt((1/T)*log2 e) = sqrt(2.8853901)
#define RES_SCALE 0.6931471805599453f  // ln2: sim = acc * ln2 after prescale

__device__ inline unsigned short f2bf(float f) {
  __hip_bfloat16 h = __float2bfloat16(f);
  return *reinterpret_cast<unsigned short*>(&h);
}

__device__ inline float fexp2(float x) {
#if __has_builtin(__builtin_amdgcn_exp2f)
  return __builtin_amdgcn_exp2f(x);  // raw v_exp_f32; args in [-2.9, 2.9]
#else
  return exp2f(x);
#endif
}

__global__ __launch_bounds__(256) void nrm_kernel(const float* __restrict__ z1,
                                                  const float* __restrict__ z2,
                                                  unsigned short* __restrict__ zn) {
  int row = blockIdx.x * 4 + (threadIdx.x >> 6);
  int lane = threadIdx.x & 63;
  const float* src = (row < B_HALF) ? (z1 + (size_t)row * D_DIM)
                                    : (z2 + (size_t)(row - B_HALF) * D_DIM);
  f32x4 v = *reinterpret_cast<const f32x4*>(src + lane * 4);
  float ss = v.x * v.x + v.y * v.y + v.z * v.z + v.w * v.w;
#pragma unroll
  for (int m = 32; m >= 1; m >>= 1) ss += __shfl_xor(ss, m);
  float inv = SCL_PRE / fmaxf(sqrtf(ss), 1e-8f);  // normalize + exp2 prescale
  ushort4 o;
  o.x = f2bf(v.x * inv);
  o.y = f2bf(v.y * inv);
  o.z = f2bf(v.z * inv);
  o.w = f2bf(v.w * inv);
  *reinterpret_cast<ushort4*>(zn + (size_t)row * D_DIM + lane * 4) = o;
}

__global__ __launch_bounds__(256, 2) void gram_kernel(const unsigned short* __restrict__ zn,
                                                      float* __restrict__ psum,
                                                      float* __restrict__ ppos) {
  const int tid = threadIdx.x;
  const int w = tid >> 6, l = tid & 63;
  const int lm = l & 15, hh = l >> 4;
  const int r0w = blockIdx.x * 256 + w * 64;  // this wave's 64 i-rows
  const int jbase = blockIdx.y * JCOLS;
  const char* znb = reinterpret_cast<const char*>(zn);

  // A fragments: 64 rows x K=256 in registers. lane: row lm (+rf*16), k-bytes
  // g*64 + hh*16 .. +15 (8 bf16). B loaded with the same per-lane pattern
  // (Gram symmetry -> any k-permutation cancels between A and B).
  s16x8 a[4][8];
#pragma unroll
  for (int rf = 0; rf < 4; ++rf)
#pragma unroll
    for (int g = 0; g < 8; ++g)
      a[rf][g] = *reinterpret_cast<const s16x8*>(
          znb + (size_t)(r0w + rf * 16 + lm) * 512 + g * 64 + hh * 16);

  float sume[4][4];
#pragma unroll
  for (int rf = 0; rf < 4; ++rf)
#pragma unroll
    for (int t = 0; t < 4; ++t) sume[rf][t] = 0.f;

  // B-fragment loader: 16-col tile jt (of 32), straight from global (L1/L2).
  auto loadB = [&](int jt, s16x8 (&b)[8]) {
    const char* base = znb + (size_t)(jbase + jt * 16 + lm) * 512 + hh * 16;
#pragma unroll
    for (int g = 0; g < 8; ++g)
      b[g] = *reinterpret_cast<const s16x8*>(base + g * 64);
  };

  // one 16-col tile: 32 MFMA + fused exp/LSE epilogue
  auto tile = [&](const s16x8 (&b)[8], int jt) {
    f32x4 ac[4];
#pragma unroll
    for (int rf = 0; rf < 4; ++rf) ac[rf] = (f32x4){0.f, 0.f, 0.f, 0.f};
    __builtin_amdgcn_s_setprio(1);
#pragma unroll
    for (int g = 0; g < 8; ++g) {
      ac[0] = __builtin_amdgcn_mfma_f32_16x16x32_bf16(a[0][g], b[g], ac[0], 0, 0, 0);
      ac[1] = __builtin_amdgcn_mfma_f32_16x16x32_bf16(a[1][g], b[g], ac[1], 0, 0, 0);
      ac[2] = __builtin_amdgcn_mfma_f32_16x16x32_bf16(a[2][g], b[g], ac[2], 0, 0, 0);
      ac[3] = __builtin_amdgcn_mfma_f32_16x16x32_bf16(a[3][g], b[g], ac[3], 0, 0, 0);
    }
    __builtin_amdgcn_s_setprio(0);
    const int jtb = jbase + jt * 16;
#pragma unroll
    for (int rf = 0; rf < 4; ++rf) {
      const int itb = r0w + rf * 16;
      const bool dg = (itb == jtb);
      const bool ps = ((itb ^ B_HALF) == jtb);
      if (dg | ps) {  // wave-uniform; at most 8 of 128 tiles per wave
#pragma unroll
        for (int t = 0; t < 4; ++t) {
          float sv = ac[rf][t];
          float e = fexp2(sv);
          bool self = (lm == hh * 4 + t);  // C/D map: row=hh*4+t, col=lm
          if (dg && self) e = 0.f;         // mask diagonal
          sume[rf][t] += e;
          if (ps && self) ppos[itb + hh * 4 + t] = sv * RES_SCALE;
        }
      } else {
#pragma unroll
        for (int t = 0; t < 4; ++t) sume[rf][t] += fexp2(ac[rf][t]);
      }
    }
  };

  // software pipeline: prefetch tile jt+1's B frags while MFMA+epilogue of jt
  s16x8 b0[8], b1[8];
  loadB(0, b0);
#pragma unroll 1
  for (int jp = 0; jp < 16; ++jp) {
    loadB(jp * 2 + 1, b1);        // in flight during tile(b0)
    tile(b0, jp * 2);
    loadB((jp * 2 + 2) & 31, b0); // jp=15 wraps to jt=0: unused, avoids branch
    tile(b1, jp * 2 + 1);
  }

  // reduce partial sums across the 16 lanes (lm) sharing each row
#pragma unroll
  for (int rf = 0; rf < 4; ++rf)
#pragma unroll
    for (int t = 0; t < 4; ++t) {
      float v = sume[rf][t];
#pragma unroll
      for (int m = 1; m < 16; m <<= 1) v += __shfl_xor(v, m);
      if (lm == 0) psum[(size_t)blockIdx.y * N_TOT + r0w + rf * 16 + hh * 4 + t] = v;
    }
}

__global__ __launch_bounds__(256) void fin1_kernel(const float* __restrict__ psum,
                                                   const float* __restrict__ ppos,
                                                   float* __restrict__ partial) {
  int i = blockIdx.x * 256 + threadIdx.x;
  float se = 0.f;
#pragma unroll
  for (int s = 0; s < JSPLIT; ++s) se += psum[(size_t)s * N_TOT + i];
  float acc = logf(se) - ppos[i];
#pragma unroll
  for (int m = 32; m >= 1; m >>= 1) acc += __shfl_xor(acc, m);
  __shared__ float red[4];
  if ((threadIdx.x & 63) == 0) red[threadIdx.x >> 6] = acc;
  __syncthreads();
  if (threadIdx.x == 0) partial[blockIdx.x] = red[0] + red[1] + red[2] + red[3];
}

__global__ void fin2_kernel(const float* __restrict__ partial, float* __restrict__ out) {
  float v = (threadIdx.x < 32) ? partial[threadIdx.x] : 0.f;
#pragma unroll
  for (int m = 32; m >= 1; m >>= 1) v += __shfl_xor(v, m);
  if (threadIdx.x == 0) out[0] = v / (float)N_TOT;
}

extern "C" void kernel_launch(void* const* d_in, const int* in_sizes, int n_in,
                              void* d_out, int out_size, void* d_ws, size_t ws_size,
                              hipStream_t stream) {
  const float* z1 = (const float*)d_in[0];
  const float* z2 = (const float*)d_in[1];
  float* out = (float*)d_out;
  char* ws = (char*)d_ws;

  unsigned short* zn = (unsigned short*)ws;                 // 4 MiB
  float* psum = (float*)(ws + (size_t)N_TOT * D_DIM * 2);   // 16*8192 f32 = 512 KiB
  float* ppos = psum + (size_t)JSPLIT * N_TOT;              // 8192 f32
  float* partial = ppos + N_TOT;                            // 32 f32

  nrm_kernel<<<N_TOT / 4, 256, 0, stream>>>(z1, z2, zn);
  gram_kernel<<<dim3(N_TOT / 256, JSPLIT), 256, 0, stream>>>(zn, psum, ppos);
  fin1_kernel<<<N_TOT / 256, 256, 0, stream>>>(psum, ppos, partial);
  fin2_kernel<<<1, 64, 0, stream>>>(partial, out);
}

// Round 8
// 49.956 us; speedup vs baseline: 1.6650x; 1.6650x over previous
//
#include <hip/hip_runtime.h>
#include <hip/hip_bf16.h>

// NT-Xent loss, MI355X. B=4096, D=256, N=8192, temp=0.5.
// normalize(+exp2 prescale) -> bf16 zn -> MFMA Gram with fused exp/LSE
// partials -> finalize.
// R8 = R6 (LDS staging, deferred epilogue, setprio) + register double-buffer
// of B fragments at half-tile (K=128 = 4 ds_read_b128) granularity: reads for
// phase p+1 issue BEFORE the MFMA of phase p, so the compiler emits counted
// lgkmcnt(4) waits and LDS latency/queueing leaves the per-wave critical path
// (R6 counters: dur ~= serial sum of MFMA 12.4us + LDS 13.6us + VALU 9us).
// Accumulator ping-pong (acA/acB, statically indexed in unrolled jt loop)
// avoids a pac copy. ~233 VGPR -> 2 waves/SIMD under (256,2), no spill
// (falsifier: WRITE_SIZE >> 10MB).
// R7 lesson: B direct-from-global = VMEM latency-bound (75us) -> LDS is right.

typedef __attribute__((ext_vector_type(4))) float f32x4;
typedef __attribute__((ext_vector_type(8))) short s16x8;

#define N_TOT 8192
#define B_HALF 4096
#define D_DIM 256
#define JSPLIT 16
#define JCOLS 512
#define NSTEP 8
#define SCL_PRE 1.6986436f             // sqrt((1/T)*log2 e) = sqrt(2.8853901)
#define RES_SCALE 0.6931471805599453f  // ln2: sim = acc * ln2 after prescale

__device__ inline unsigned short f2bf(float f) {
  __hip_bfloat16 h = __float2bfloat16(f);
  return *reinterpret_cast<unsigned short*>(&h);
}

__device__ inline float fexp2(float x) {
#if __has_builtin(__builtin_amdgcn_exp2f)
  return __builtin_amdgcn_exp2f(x);  // raw v_exp_f32; args in [-2.9, 2.9]
#else
  return exp2f(x);
#endif
}

__global__ __launch_bounds__(256) void nrm_kernel(const float* __restrict__ z1,
                                                  const float* __restrict__ z2,
                                                  unsigned short* __restrict__ zn) {
  int row = blockIdx.x * 4 + (threadIdx.x >> 6);
  int lane = threadIdx.x & 63;
  const float* src = (row < B_HALF) ? (z1 + (size_t)row * D_DIM)
                                    : (z2 + (size_t)(row - B_HALF) * D_DIM);
  f32x4 v = *reinterpret_cast<const f32x4*>(src + lane * 4);
  float ss = v.x * v.x + v.y * v.y + v.z * v.z + v.w * v.w;
#pragma unroll
  for (int m = 32; m >= 1; m >>= 1) ss += __shfl_xor(ss, m);
  float inv = SCL_PRE / fmaxf(sqrtf(ss), 1e-8f);  // normalize + exp2 prescale
  ushort4 o;
  o.x = f2bf(v.x * inv);
  o.y = f2bf(v.y * inv);
  o.z = f2bf(v.z * inv);
  o.w = f2bf(v.w * inv);
  *reinterpret_cast<ushort4*>(zn + (size_t)row * D_DIM + lane * 4) = o;
}

__global__ __launch_bounds__(256, 2) void gram_kernel(const unsigned short* __restrict__ zn,
                                                      float* __restrict__ psum,
                                                      float* __restrict__ ppos) {
  __shared__ __align__(16) char bt[2 * 64 * 512];  // double-buffered 64-row B tiles
  const int tid = threadIdx.x;
  const int w = tid >> 6, l = tid & 63;
  const int lm = l & 15, hh = l >> 4;
  const int r0w = blockIdx.x * 256 + w * 64;  // this wave's 64 i-rows
  const int jbase = blockIdx.y * JCOLS;
  const char* znb = reinterpret_cast<const char*>(zn);

  // stage step s (64 B-rows) into buffer bi. LDS dest linear (lane*16);
  // swizzle realized by XOR-permuting the global source within each 512B row.
  auto stage = [&](int s, int bi) {
    const char* gs = znb + (size_t)(jbase + s * 64) * 512;
    char* ldsbase = bt + bi * 32768 + (w * 16) * 512;
#pragma unroll
    for (int q = 0; q < 8; ++q) {
      int rloc = w * 16 + q * 2 + (l >> 5);
      const char* g = gs + (size_t)rloc * 512 + (((l & 31) * 16) ^ ((rloc & 7) << 4));
      __builtin_amdgcn_global_load_lds(
          (const __attribute__((address_space(1))) void*)g,
          (__attribute__((address_space(3))) void*)(ldsbase + q * 1024), 16, 0, 0);
    }
  };

  stage(0, 0);  // prefetch first tile; overlaps the A-fragment loads below

  // A fragments: 64 rows x K=256 in registers. lane: row lm (+rf*16), k-bytes
  // g*64 + hh*16 .. +15 (8 bf16). Same layout as B frags (Gram symmetry).
  s16x8 a[4][8];
#pragma unroll
  for (int rf = 0; rf < 4; ++rf)
#pragma unroll
    for (int g = 0; g < 8; ++g)
      a[rf][g] = *reinterpret_cast<const s16x8*>(
          znb + (size_t)(r0w + rf * 16 + lm) * 512 + g * 64 + hh * 16);

  float sume[4][4];
#pragma unroll
  for (int rf = 0; rf < 4; ++rf)
#pragma unroll
    for (int t = 0; t < 4; ++t) sume[rf][t] = 0.f;

  const int swz = (lm & 7) << 4;

  // register B buffers: half-tile = 4 ds_read_b128 (16 cols x K=128)
  s16x8 bh0[4], bh1[4];
  // ping-pong accumulators (statically indexed in the unrolled jt loop)
  f32x4 acA[4], acB[4];
  int pjtb = -1;

  // read half-tile: cols of jt, k-groups gbase..gbase+3
  auto read4 = [&](const char* bp, int jt, int gbase, s16x8 (&b)[4]) {
    const char* br = bp + (jt * 16 + lm) * 512;
#pragma unroll
    for (int g = 0; g < 4; ++g)
      b[g] = *reinterpret_cast<const s16x8*>(br + (((gbase + g) * 64 + hh * 16) ^ swz));
  };

  // epilogue of a finished tile: exp + LSE partial + diag mask + positive
  auto epilogue = [&](const f32x4 (&pa)[4], int jtb) {
#pragma unroll
    for (int rf = 0; rf < 4; ++rf) {
      const int itb = r0w + rf * 16;
      const bool dg = (itb == jtb);
      const bool ps = ((itb ^ B_HALF) == jtb);
      if (dg | ps) {  // wave-uniform; at most 8 of 128 tiles per wave
#pragma unroll
        for (int t = 0; t < 4; ++t) {
          float sv = pa[rf][t];
          float e = fexp2(sv);
          bool self = (lm == hh * 4 + t);  // C/D map: row=hh*4+t, col=lm
          if (dg && self) e = 0.f;         // mask diagonal
          sume[rf][t] += e;
          if (ps && self) ppos[itb + hh * 4 + t] = sv * RES_SCALE;
        }
      } else {
#pragma unroll
        for (int t = 0; t < 4; ++t) sume[rf][t] += fexp2(pa[rf][t]);
      }
    }
  };

  auto mfma16 = [&](f32x4 (&acc)[4], const s16x8 (&b)[4], int gbase) {
    __builtin_amdgcn_s_setprio(1);
#pragma unroll
    for (int g = 0; g < 4; ++g) {
      acc[0] = __builtin_amdgcn_mfma_f32_16x16x32_bf16(a[0][gbase + g], b[g], acc[0], 0, 0, 0);
      acc[1] = __builtin_amdgcn_mfma_f32_16x16x32_bf16(a[1][gbase + g], b[g], acc[1], 0, 0, 0);
      acc[2] = __builtin_amdgcn_mfma_f32_16x16x32_bf16(a[2][gbase + g], b[g], acc[2], 0, 0, 0);
      acc[3] = __builtin_amdgcn_mfma_f32_16x16x32_bf16(a[3][gbase + g], b[g], acc[3], 0, 0, 0);
    }
    __builtin_amdgcn_s_setprio(0);
  };

  for (int s = 0; s < NSTEP; ++s) {
    __syncthreads();  // drains my stage loads (vmcnt0) + all waves done w/ prev buf
    if (s + 1 < NSTEP) stage(s + 1, (s + 1) & 1);  // async prefetch under compute
    const char* bp = bt + (s & 1) * 32768;

    read4(bp, 0, 0, bh0);  // prologue: first half-tile of this step
#pragma unroll
    for (int jt = 0; jt < 4; ++jt) {
      // static ping-pong: tile parity alternates strictly (incl. across steps)
      f32x4(&acc)[4] = (jt & 1) ? acB : acA;
      f32x4(&prev)[4] = (jt & 1) ? acA : acB;

      read4(bp, jt, 4, bh1);              // in flight during epilogue + MFMA(bh0)
      if (pjtb >= 0) epilogue(prev, pjtb);  // VALU under read latency
#pragma unroll
      for (int rf = 0; rf < 4; ++rf) acc[rf] = (f32x4){0.f, 0.f, 0.f, 0.f};
      mfma16(acc, bh0, 0);                // waits lgkmcnt(4), not 0
      if (jt < 3) read4(bp, jt + 1, 0, bh0);  // in flight during MFMA(bh1)
      mfma16(acc, bh1, 4);
      pjtb = jbase + s * 64 + jt * 16;
    }
  }
  epilogue(acB, pjtb);  // last tile was jt=3 -> acB

  // reduce partial sums across the 16 lanes (lm) sharing each row
#pragma unroll
  for (int rf = 0; rf < 4; ++rf)
#pragma unroll
    for (int t = 0; t < 4; ++t) {
      float v = sume[rf][t];
#pragma unroll
      for (int m = 1; m < 16; m <<= 1) v += __shfl_xor(v, m);
      if (lm == 0) psum[(size_t)blockIdx.y * N_TOT + r0w + rf * 16 + hh * 4 + t] = v;
    }
}

__global__ __launch_bounds__(256) void fin1_kernel(const float* __restrict__ psum,
                                                   const float* __restrict__ ppos,
                                                   float* __restrict__ partial) {
  int i = blockIdx.x * 256 + threadIdx.x;
  float se = 0.f;
#pragma unroll
  for (int s = 0; s < JSPLIT; ++s) se += psum[(size_t)s * N_TOT + i];
  float acc = logf(se) - ppos[i];
#pragma unroll
  for (int m = 32; m >= 1; m >>= 1) acc += __shfl_xor(acc, m);
  __shared__ float red[4];
  if ((threadIdx.x & 63) == 0) red[threadIdx.x >> 6] = acc;
  __syncthreads();
  if (threadIdx.x == 0) partial[blockIdx.x] = red[0] + red[1] + red[2] + red[3];
}

__global__ void fin2_kernel(const float* __restrict__ partial, float* __restrict__ out) {
  float v = (threadIdx.x < 32) ? partial[threadIdx.x] : 0.f;
#pragma unroll
  for (int m = 32; m >= 1; m >>= 1) v += __shfl_xor(v, m);
  if (threadIdx.x == 0) out[0] = v / (float)N_TOT;
}

extern "C" void kernel_launch(void* const* d_in, const int* in_sizes, int n_in,
                              void* d_out, int out_size, void* d_ws, size_t ws_size,
                              hipStream_t stream) {
  const float* z1 = (const float*)d_in[0];
  const float* z2 = (const float*)d_in[1];
  float* out = (float*)d_out;
  char* ws = (char*)d_ws;

  unsigned short* zn = (unsigned short*)ws;                 // 4 MiB
  float* psum = (float*)(ws + (size_t)N_TOT * D_DIM * 2);   // 16*8192 f32 = 512 KiB
  float* ppos = psum + (size_t)JSPLIT * N_TOT;              // 8192 f32
  float* partial = ppos + N_TOT;                            // 32 f32

  nrm_kernel<<<N_TOT / 4, 256, 0, stream>>>(z1, z2, zn);
  gram_kernel<<<dim3(N_TOT / 256, JSPLIT), 256, 0, stream>>>(zn, psum, ppos);
  fin1_kernel<<<N_TOT / 256, 256, 0, stream>>>(psum, ppos, partial);
  fin2_kernel<<<1, 64, 0, stream>>>(partial, out);
}

// Round 9
// 36.603 us; speedup vs baseline: 2.2724x; 1.3648x over previous
//
#include <hip/hip_runtime.h>
#include <hip/hip_bf16.h>
#if !__has_builtin(__builtin_amdgcn_cvt_pk_fp8_f32)
#include <hip/hip_fp8.h>
#endif

// NT-Xent loss, MI355X. B=4096, D=256, N=8192, temp=0.5.
// R9: fp8(e4m3) MX-scaled MFMA (mfma_scale_f32_16x16x128_f8f6f4, scale=1.0
// via 0x7F bytes) on the R8 skeleton. Halves every pole vs bf16: MFMA
// 16.6->7.4us (2x rate), LDS bytes /2 (1B/elem; 32B/lane slice feeds 4 MFMA
// = 128 FLOP/LDS-byte), A-frags 128->64 VGPR. R4-R8 showed dur ~= serial sum
// of poles at 2 waves/SIMD; shrinking poles beats rescheduling them.
// Accuracy: unit-norm rows -> quant RMS on sim ~0.01, mean-loss err ~1e-3
// << 0.18 threshold. Gram symmetry makes fp8 pack order and k-permutations
// correctness-irrelevant (same permutation hits both operands of every dot).
// Layout per lane (A and B identical = mirrored operands): row l&15,
// k-bytes (l>>4)*32 within each K=128 slice. C/D map row=(l>>4)*4+t, col=l&15
// (shape-determined, dtype-independent per m121-m128).

typedef __attribute__((ext_vector_type(4))) float f32x4;
typedef __attribute__((ext_vector_type(8))) int i32x8;

#define N_TOT 8192
#define B_HALF 4096
#define D_DIM 256
#define JSPLIT 16
#define JCOLS 512
#define NSTEP 8
#define SCL_PRE 1.6986436f             // sqrt((1/T)*log2 e) = sqrt(2.8853901)
#define RES_SCALE 0.6931471805599453f  // ln2: sim = acc * ln2 after prescale
#define SONE 0x7F7F7F7F                // E8M0 scale bytes = 127 -> 2^0 = 1.0

__device__ inline float fexp2(float x) {
#if __has_builtin(__builtin_amdgcn_exp2f)
  return __builtin_amdgcn_exp2f(x);  // raw v_exp_f32; args in [-2.9, 2.9]
#else
  return exp2f(x);
#endif
}

__device__ inline unsigned pack_fp8x4(float x, float y, float z, float w) {
#if __has_builtin(__builtin_amdgcn_cvt_pk_fp8_f32)
  int r = 0;
  r = __builtin_amdgcn_cvt_pk_fp8_f32(x, y, r, false);  // bytes 0,1
  r = __builtin_amdgcn_cvt_pk_fp8_f32(z, w, r, true);   // bytes 2,3
  return (unsigned)r;
#else
  __hip_fp8_e4m3 a(x), b(y), c(z), d(w);
  return (unsigned)a.__x | ((unsigned)b.__x << 8) | ((unsigned)c.__x << 16) |
         ((unsigned)d.__x << 24);
#endif
}

__device__ inline i32x8 ld32(const char* p0, const char* p1) {
  int4 lo = *reinterpret_cast<const int4*>(p0);
  int4 hi = *reinterpret_cast<const int4*>(p1);
  i32x8 r = {lo.x, lo.y, lo.z, lo.w, hi.x, hi.y, hi.z, hi.w};
  return r;
}

__global__ __launch_bounds__(256) void nrm_kernel(const float* __restrict__ z1,
                                                  const float* __restrict__ z2,
                                                  unsigned* __restrict__ zn8) {
  int row = blockIdx.x * 4 + (threadIdx.x >> 6);
  int lane = threadIdx.x & 63;
  const float* src = (row < B_HALF) ? (z1 + (size_t)row * D_DIM)
                                    : (z2 + (size_t)(row - B_HALF) * D_DIM);
  f32x4 v = *reinterpret_cast<const f32x4*>(src + lane * 4);
  float ss = v.x * v.x + v.y * v.y + v.z * v.z + v.w * v.w;
#pragma unroll
  for (int m = 32; m >= 1; m >>= 1) ss += __shfl_xor(ss, m);
  float inv = SCL_PRE / fmaxf(sqrtf(ss), 1e-8f);  // normalize + exp2 prescale
  zn8[(size_t)row * 64 + lane] =
      pack_fp8x4(v.x * inv, v.y * inv, v.z * inv, v.w * inv);
}

__global__ __launch_bounds__(256, 2) void gram_kernel(const unsigned* __restrict__ zn8,
                                                      float* __restrict__ psum,
                                                      float* __restrict__ ppos) {
  __shared__ __align__(16) char bt[2 * 64 * 256];  // double-buffered fp8 B panels
  const int tid = threadIdx.x;
  const int w = tid >> 6, l = tid & 63;
  const int lm = l & 15, hh = l >> 4;
  const int r0w = blockIdx.x * 256 + w * 64;  // this wave's 64 i-rows
  const int jbase = blockIdx.y * JCOLS;
  const char* znb = reinterpret_cast<const char*>(zn8);

  // stage step s (64 B-rows x 256B fp8) into buffer bi. LDS dest linear
  // (uniform base + lane*16); swizzle realized by XOR on the global source.
  auto stage = [&](int s, int bi) {
    const char* gs = znb + (size_t)(jbase + s * 64) * 256;
    char* base = bt + bi * 16384 + w * 1024;
#pragma unroll
    for (int q = 0; q < 4; ++q) {
      int rloc = q * 16 + w * 4 + (l >> 4);
      const char* g = gs + (size_t)rloc * 256 + (((l & 15) * 16) ^ ((rloc & 7) << 4));
      __builtin_amdgcn_global_load_lds(
          (const __attribute__((address_space(1))) void*)g,
          (__attribute__((address_space(3))) void*)(base + q * 4096), 16, 0, 0);
    }
  };

  stage(0, 0);  // prefetch first panel; overlaps the A-fragment loads below

  // A fragments: 64 rows x K=256 fp8 in registers. lane: row lm (+rf*16),
  // k-bytes sl*128 + hh*32 .. +31. B mirrors this (Gram symmetry).
  i32x8 a[4][2];
#pragma unroll
  for (int rf = 0; rf < 4; ++rf)
#pragma unroll
    for (int sl = 0; sl < 2; ++sl) {
      const char* ab = znb + (size_t)(r0w + rf * 16 + lm) * 256 + sl * 128 + hh * 32;
      a[rf][sl] = ld32(ab, ab + 16);
    }

  float sume[4][4];
#pragma unroll
  for (int rf = 0; rf < 4; ++rf)
#pragma unroll
    for (int t = 0; t < 4; ++t) sume[rf][t] = 0.f;

  const int swz = (lm & 7) << 4;  // row = jt*16+lm -> row&7 == lm&7

  i32x8 bh0, bh1;         // register-double-buffered B slices (K=128 each)
  f32x4 acA[4], acB[4];   // ping-pong accumulators (static indexing)
  int pjtb = -1;

  // read one B slice: 16 cols x K=128 = 32B/lane, two swizzled ds_read_b128
  auto readS = [&](const char* bp, int jt, int sl, i32x8& b) {
    const char* row = bp + (jt * 16 + lm) * 256;
    int cs = (sl * 128 + hh * 32) ^ swz;
    b = ld32(row + cs, row + (cs ^ 16));
  };

  // epilogue of a finished tile: exp + LSE partial + diag mask + positive
  auto epilogue = [&](const f32x4 (&pa)[4], int jtb) {
#pragma unroll
    for (int rf = 0; rf < 4; ++rf) {
      const int itb = r0w + rf * 16;
      const bool dg = (itb == jtb);
      const bool ps = ((itb ^ B_HALF) == jtb);
      if (dg | ps) {  // wave-uniform; at most 8 of 128 tiles per wave
#pragma unroll
        for (int t = 0; t < 4; ++t) {
          float sv = pa[rf][t];
          float e = fexp2(sv);
          bool self = (lm == hh * 4 + t);  // C/D map: row=hh*4+t, col=lm
          if (dg && self) e = 0.f;         // mask diagonal
          sume[rf][t] += e;
          if (ps && self) ppos[itb + hh * 4 + t] = sv * RES_SCALE;
        }
      } else {
#pragma unroll
        for (int t = 0; t < 4; ++t) sume[rf][t] += fexp2(pa[rf][t]);
      }
    }
  };

  auto mfma4 = [&](f32x4 (&acc)[4], const i32x8& b, int sl) {
    __builtin_amdgcn_s_setprio(1);
#pragma unroll
    for (int rf = 0; rf < 4; ++rf)
      acc[rf] = __builtin_amdgcn_mfma_scale_f32_16x16x128_f8f6f4(
          a[rf][sl], b, acc[rf], 0, 0, 0, SONE, 0, SONE);
    __builtin_amdgcn_s_setprio(0);
  };

  for (int s = 0; s < NSTEP; ++s) {
    __syncthreads();  // drains my stage loads + all waves done w/ prev buf
    if (s + 1 < NSTEP) stage(s + 1, (s + 1) & 1);  // async prefetch under compute
    const char* bp = bt + (s & 1) * 16384;

    readS(bp, 0, 0, bh0);  // prologue: first slice of this step
#pragma unroll
    for (int jt = 0; jt < 4; ++jt) {
      f32x4(&acc)[4] = (jt & 1) ? acB : acA;
      f32x4(&prev)[4] = (jt & 1) ? acA : acB;

      readS(bp, jt, 1, bh1);                // in flight during epilogue+MFMA
      if (pjtb >= 0) epilogue(prev, pjtb);  // VALU under read latency
#pragma unroll
      for (int rf = 0; rf < 4; ++rf) acc[rf] = (f32x4){0.f, 0.f, 0.f, 0.f};
      mfma4(acc, bh0, 0);
      if (jt < 3) readS(bp, jt + 1, 0, bh0);  // in flight during MFMA(bh1)
      mfma4(acc, bh1, 1);
      pjtb = jbase + s * 64 + jt * 16;
    }
  }
  epilogue(acB, pjtb);  // last tile was jt=3 -> acB

  // reduce partial sums across the 16 lanes (lm) sharing each row
#pragma unroll
  for (int rf = 0; rf < 4; ++rf)
#pragma unroll
    for (int t = 0; t < 4; ++t) {
      float v = sume[rf][t];
#pragma unroll
      for (int m = 1; m < 16; m <<= 1) v += __shfl_xor(v, m);
      if (lm == 0) psum[(size_t)blockIdx.y * N_TOT + r0w + rf * 16 + hh * 4 + t] = v;
    }
}

__global__ __launch_bounds__(256) void fin1_kernel(const float* __restrict__ psum,
                                                   const float* __restrict__ ppos,
                                                   float* __restrict__ partial) {
  int i = blockIdx.x * 256 + threadIdx.x;
  float se = 0.f;
#pragma unroll
  for (int s = 0; s < JSPLIT; ++s) se += psum[(size_t)s * N_TOT + i];
  float acc = logf(se) - ppos[i];
#pragma unroll
  for (int m = 32; m >= 1; m >>= 1) acc += __shfl_xor(acc, m);
  __shared__ float red[4];
  if ((threadIdx.x & 63) == 0) red[threadIdx.x >> 6] = acc;
  __syncthreads();
  if (threadIdx.x == 0) partial[blockIdx.x] = red[0] + red[1] + red[2] + red[3];
}

__global__ void fin2_kernel(const float* __restrict__ partial, float* __restrict__ out) {
  float v = (threadIdx.x < 32) ? partial[threadIdx.x] : 0.f;
#pragma unroll
  for (int m = 32; m >= 1; m >>= 1) v += __shfl_xor(v, m);
  if (threadIdx.x == 0) out[0] = v / (float)N_TOT;
}

extern "C" void kernel_launch(void* const* d_in, const int* in_sizes, int n_in,
                              void* d_out, int out_size, void* d_ws, size_t ws_size,
                              hipStream_t stream) {
  const float* z1 = (const float*)d_in[0];
  const float* z2 = (const float*)d_in[1];
  float* out = (float*)d_out;
  char* ws = (char*)d_ws;

  unsigned* zn8 = (unsigned*)ws;                            // 2 MiB fp8
  float* psum = (float*)(ws + (size_t)N_TOT * D_DIM);       // 16*8192 f32
  float* ppos = psum + (size_t)JSPLIT * N_TOT;              // 8192 f32
  float* partial = ppos + N_TOT;                            // 32 f32

  nrm_kernel<<<N_TOT / 4, 256, 0, stream>>>(z1, z2, zn8);
  gram_kernel<<<dim3(N_TOT / 256, JSPLIT), 256, 0, stream>>>(zn8, psum, ppos);
  fin1_kernel<<<N_TOT / 256, 256, 0, stream>>>(psum, ppos, partial);
  fin2_kernel<<<1, 64, 0, stream>>>(partial, out);
}